// Round 6
// baseline (477.997 us; speedup 1.0000x reference)
//
#include <hip/hip_runtime.h>
#include <hip/hip_bf16.h>

// Problem constants
#define NB    8
#define SQN   2048
#define SKN   4096
#define DDIM  512
#define DVDIM 256
#define NROWS (NB*SQN)      // 16384
#define NS    2             // SK splits
#define NJ    ((SKN/64)/NS) // 32 j-iterations per split (64 keys each)

typedef __attribute__((ext_vector_type(8)))  short bf16x8;   // 8 bf16 = 4 VGPRs (MFMA A/B frag)
typedef __attribute__((ext_vector_type(4)))  short bf16x4;
typedef __attribute__((ext_vector_type(4)))  float f32x4;    // 16x16 MFMA C/D frag
typedef __attribute__((ext_vector_type(16))) float f32x16;   // 32x32 MFMA C/D frag

// fp32 -> bf16 round-to-nearest-even, bit pattern as short
__device__ __forceinline__ short f2bf(float f) {
    unsigned u = __float_as_uint(f);
    return (short)((u + 0x7FFFu + ((u >> 16) & 1u)) >> 16);
}

// LDS-only barrier: vm loads (K/V register prefetches) stay in flight.
// sched_barrier fences per rule #18 (no hoisting across the asm wait).
#define BAR_LGKM() do {                                                       \
    asm volatile("s_waitcnt lgkmcnt(0)" ::: "memory");                        \
    __builtin_amdgcn_sched_barrier(0);                                        \
    __builtin_amdgcn_s_barrier();                                             \
    __builtin_amdgcn_sched_barrier(0);                                        \
} while (0)

// ---------------------------------------------------------------------------
// Fused projection GEMMs, one launch. grid = (64, 8, 2).  (unchanged)
//  z=0: key[s][d]  = sum_c Y[s][c]*Wk[d][c]   M=4096 N=512
//  z=1: vt[dv][s]  = sum_c Wv[dv][c]*Z[s][c]  M=256  N=4096 (uses 256 of 512 tiles)
// ---------------------------------------------------------------------------
__global__ __launch_bounds__(256, 2) void proj_gemms(
    const float* __restrict__ Y, const float* __restrict__ Z,
    const float* __restrict__ Wk, const float* __restrict__ Wv,
    unsigned short* __restrict__ keyb, unsigned short* __restrict__ vtb)
{
    __shared__ short sA[64*128];   // 16 KB
    __shared__ short sB[64*128];   // 16 KB
    const float *A, *Bm;
    unsigned short* C;
    int N, m0, n0;
    if (blockIdx.z == 0) {
        A = Y; Bm = Wk; C = keyb; N = DDIM;
        m0 = blockIdx.x * 64; n0 = blockIdx.y * 64;
    } else {
        int lin = blockIdx.x * 8 + blockIdx.y;
        if (lin >= 256) return;                 // value GEMM needs 256 tiles
        A = Wv; Bm = Z; C = vtb; N = SKN;
        m0 = (lin >> 6) * 64; n0 = (lin & 63) * 64;
    }
    const int tid  = threadIdx.x;
    const int wave = tid >> 6;
    const int lane = tid & 63;
    const int quad = lane >> 4;
    const int l15  = lane & 15;

    f32x4 acc[4];
    #pragma unroll
    for (int n = 0; n < 4; ++n) { acc[n][0]=0.f; acc[n][1]=0.f; acc[n][2]=0.f; acc[n][3]=0.f; }

    float4 ra[8], rb[8];
    #pragma unroll
    for (int it = 0; it < 8; ++it) {            // prefetch kc=0
        int f = it*1024 + tid*4, row = f >> 7, col = f & 127;
        ra[it] = *(const float4*)(A  + (size_t)(m0+row)*DDIM + col);
        rb[it] = *(const float4*)(Bm + (size_t)(n0+row)*DDIM + col);
    }

    for (int kc = 0; kc < DDIM; kc += 128) {
        __syncthreads();                        // LDS free (prev MFMA done)
        #pragma unroll
        for (int it = 0; it < 8; ++it) {
            int f = it*1024 + tid*4;
            bf16x4 a4; a4[0]=f2bf(ra[it].x); a4[1]=f2bf(ra[it].y); a4[2]=f2bf(ra[it].z); a4[3]=f2bf(ra[it].w);
            *(bf16x4*)(sA + f) = a4;
            bf16x4 b4; b4[0]=f2bf(rb[it].x); b4[1]=f2bf(rb[it].y); b4[2]=f2bf(rb[it].z); b4[3]=f2bf(rb[it].w);
            *(bf16x4*)(sB + f) = b4;
        }
        __syncthreads();                        // staged visible
        if (kc + 128 < DDIM) {                  // prefetch kc+1 (in flight under MFMA)
            #pragma unroll
            for (int it = 0; it < 8; ++it) {
                int f = it*1024 + tid*4, row = f >> 7, col = f & 127;
                ra[it] = *(const float4*)(A  + (size_t)(m0+row)*DDIM + kc + 128 + col);
                rb[it] = *(const float4*)(Bm + (size_t)(n0+row)*DDIM + kc + 128 + col);
            }
        }
        #pragma unroll
        for (int t = 0; t < 4; ++t) {
            bf16x8 af = *(const bf16x8*)(sA + (wave*16 + l15)*128 + t*32 + quad*8);
            #pragma unroll
            for (int n = 0; n < 4; ++n) {
                bf16x8 bfr = *(const bf16x8*)(sB + (n*16 + l15)*128 + t*32 + quad*8);
                acc[n] = __builtin_amdgcn_mfma_f32_16x16x32_bf16(af, bfr, acc[n], 0, 0, 0);
            }
        }
    }
    #pragma unroll
    for (int n = 0; n < 4; ++n)
        #pragma unroll
        for (int r = 0; r < 4; ++r) {
            int m  = m0 + wave*16 + quad*4 + r;
            int nn = n0 + n*16 + l15;
            C[(size_t)m*N + nn] = (unsigned short)f2bf(acc[n][r]);
        }
}

// ---------------------------------------------------------------------------
// Fused attention, R6 (= R5 with two audit fixes):
//  FIX 1: V frag stream includes the wave's dv-half offset (wk*128) —
//         R5 read dv 0..127 for both wk waves (wrong V rows for wk=1).
//  FIX 2: register relief — Q frags for half-chunks h=6,7 live in
//         wave-private LDS (8 x 1KB/wave, 64 KB total); qf[24] in regs.
//         Peak live ~230 VGPR < 256 (R5 was ~270 -> spill, the R1 mode).
// Structure: K/V fragments load GLOBAL -> REGISTERS directly (frag = 16
// contiguous B/lane in natural layout); LDS only for Q-spill + P/stat
// exchange; 2 lgkm-only barriers/j (no staging barriers at all); waves
// free-run -> MFMA/VALU/VMEM overlap organically (R3/R4 diagnosis: LDS
// staging forced block-wide barriers that serialized the pipes).
// wm-duplicated K reads served by L1 (16 KB chunk fits). XCD-split swizzle
// keeps K/V L2-resident. T13 defer-max (log2 domain, THR=8); scale*log2e
// folded into Q so softmax is raw exp2 (Mpart log2-domain; combine matches).
// grid = 256 (1 block/CU), block = 512 (8 waves: wm=0..3 x wk=0..1).
// ---------------------------------------------------------------------------
__global__ __launch_bounds__(512, 2) void attn_fused(
    const float* __restrict__ X,            // [16384][512] fp32
    const unsigned short* __restrict__ Kb,  // key bf16 [4096][512] natural
    const unsigned short* __restrict__ Vt,  // V^T bf16 [256][4096] natural
    float* __restrict__ Opart,              // [NS][16384][256]
    float* __restrict__ Mpart,              // [NS][16384] (log2 domain)
    float* __restrict__ Lpart)              // [NS][16384]
{
    // 0     : sQ 64KB: [wave=8][frag=8][lane]x16B (Q half-chunks 6,7; wave-private)
    // 65536 : sPex 16KB [wm=4][g=4][lane]x16B P A-frags
    // 81920 : sSt 2KB [wave=8][slot=2][32] floats
    __shared__ __align__(16) char smem[83968];
    char* sQw  = smem + (threadIdx.x >> 6)*8192;   // this wave's Q-spill
    char* sPex = smem + 65536;
    float* sSt = (float*)(smem + 81920);

    const int tid  = threadIdx.x;
    const int wave = tid >> 6;      // 0..7
    const int lane = tid & 63;
    const int l31  = lane & 31;
    const int hi   = lane >> 5;
    const int wm   = wave >> 1;     // 0..3: Q-row group
    const int wk   = wave & 1;      // key-half for QK / dv-half for PV

    // XCD-split swizzle: bid&7 = XCD; XCD 0-3 -> split 0, 4-7 -> split 1.
    const int bid   = blockIdx.x;          // 0..255
    const int xcd   = bid & 7;
    const int slot  = bid >> 3;            // 0..31
    const int split = xcd >> 2;
    const int q0    = ((xcd & 3)*32 + slot) * 128;
    // 1/sqrt(512) * log2(e): softmax runs in log2 domain (exp2)
    const float scale = 0.04419417382415922f * 1.4426950408889634f;

    // Q as MFMA B-frags (swapped QK: B[k=d][col=q]), scale folded.
    // t<24 in regs (96 VGPR); t=24..31 in wave-private LDS (no barrier:
    // same-wave ds_write->ds_read, compiler inserts the lgkm wait).
    bf16x8 qf[24];
    {
        const float* xrow = X + (size_t)(q0 + wm*32 + l31)*DDIM + hi*8;
        #pragma unroll
        for (int t = 0; t < 32; ++t) {
            float4 a = *(const float4*)(xrow + t*16);
            float4 b = *(const float4*)(xrow + t*16 + 4);
            bf16x8 q;
            q[0]=f2bf(a.x*scale); q[1]=f2bf(a.y*scale); q[2]=f2bf(a.z*scale); q[3]=f2bf(a.w*scale);
            q[4]=f2bf(b.x*scale); q[5]=f2bf(b.y*scale); q[6]=f2bf(b.z*scale); q[7]=f2bf(b.w*scale);
            if (t < 24) qf[t] = q;
            else        *(bf16x8*)(sQw + (t - 24)*1024 + lane*16) = q;
        }
    }

    // O acc: D[row=q][col=dv], wave's dv-half = wk*128 + n*32 + l31. 64 VGPR.
    f32x16 o[4];
    #pragma unroll
    for (int n = 0; n < 4; ++n)
        #pragma unroll
        for (int r = 0; r < 16; ++r) o[n][r] = 0.f;
    float m_r = -1e30f, l_r = 0.f;       // shared across wk pair (identical by induction)

    const int jt0 = split * (NJ*64);

    // K frag stream: lane reads K[jtb + wk*32 + l31][col .. col+7], 16B.
    // A-frag for mfma(K,Q): row=key(l31), k-cols = h*64 + t*16 + hi*8.
    const unsigned short* krow = Kb + (size_t)(jt0 + wk*32 + l31)*DDIM + hi*8;
    // V frag stream: B-frag for mfma(P,V): col = dv = wk*128 + n*32 + l31,
    // k = g*16 + hi*8.  (FIX 1: wk*128 dv-half offset.)
    const unsigned short* vrow = Vt + (size_t)(wk*128 + l31)*SKN + hi*8;

    bf16x8 kf[2][4];                    // QK half-chunk double buffer (32 VGPR)
    bf16x8 vf[2][4];                    // PV window double buffer (32 VGPR)

    // prologue: load j=0 half-chunk 0
    #pragma unroll
    for (int t = 0; t < 4; ++t) kf[0][t] = *(const bf16x8*)(krow + t*16);

    for (int j = 0; j < NJ; ++j) {
        const int jtb = jt0 + j*64;
        f32x16 s;                       // P^T acc: D[row=key][col=q]
        #pragma unroll
        for (int r = 0; r < 16; ++r) s[r] = 0.f;

        // ---- QK: 8 half-chunks of 64 d; prefetch h+1 while computing h;
        //      Q frags from regs (h<6) or wave-private LDS (h>=6) ----
        #pragma unroll
        for (int h = 0; h < 8; ++h) {
            if (h < 7) {
                const unsigned short* ka = krow + (h + 1)*64;
                #pragma unroll
                for (int t = 0; t < 4; ++t)
                    kf[(h + 1) & 1][t] = *(const bf16x8*)(ka + t*16);
            }
            __builtin_amdgcn_s_setprio(1);
            #pragma unroll
            for (int t = 0; t < 4; ++t) {
                bf16x8 qv = (h < 6) ? qf[h*4 + t]
                    : *(const bf16x8*)(sQw + ((h - 6)*4 + t)*1024 + lane*16);
                s = __builtin_amdgcn_mfma_f32_32x32x16_bf16(
                        kf[h & 1][t], qv, s, 0, 0, 0);
            }
            __builtin_amdgcn_s_setprio(0);
        }

        // issue V window g=0 now: latency hides under softmax
        #pragma unroll
        for (int n = 0; n < 4; ++n)
            vf[0][n] = *(const bf16x8*)(vrow + (size_t)(n*32)*SKN + jtb);

        // ---- softmax (log2 domain), in-lane; joint max across wk pair ----
        float tmax = fmaxf(fmaxf(fmaxf(s[0],s[1]),fmaxf(s[2],s[3])),
                           fmaxf(fmaxf(s[4],s[5]),fmaxf(s[6],s[7])));
        tmax = fmaxf(tmax, fmaxf(fmaxf(fmaxf(s[8],s[9]),fmaxf(s[10],s[11])),
                                 fmaxf(fmaxf(s[12],s[13]),fmaxf(s[14],s[15]))));
        tmax = fmaxf(tmax, __shfl_xor(tmax, 32));
        if (lane < 32) sSt[(wave*2 + 0)*32 + lane] = tmax;
        BAR_LGKM();                                             // exchange 1
        float tmax_o = sSt[((wave^1)*2 + 0)*32 + l31];
        const float tj   = fmaxf(tmax, tmax_o);
        // T13 defer-max: only move the reference when it grew by >8 (p <= 2^8)
        const bool  upd  = tj > m_r + 8.0f;
        const float mn   = upd ? tj : m_r;
        float tsum = 0.f;
        #pragma unroll
        for (int r = 0; r < 16; ++r) { float pv = exp2f(s[r] - mn); s[r] = pv; tsum += pv; }
        tsum += __shfl_xor(tsum, 32);

        // P -> PV A-frags in-register (cvt_pk + permlane32_swap, proven R1-R4)
        bf16x8 pf[2];
        #pragma unroll
        for (int ks = 0; ks < 2; ++ks) {
            int wA, wB, wC, wD;
            asm("v_cvt_pk_bf16_f32 %0, %1, %2" : "=v"(wA) : "v"(s[8*ks+0]), "v"(s[8*ks+1]));
            asm("v_cvt_pk_bf16_f32 %0, %1, %2" : "=v"(wB) : "v"(s[8*ks+2]), "v"(s[8*ks+3]));
            asm("v_cvt_pk_bf16_f32 %0, %1, %2" : "=v"(wC) : "v"(s[8*ks+4]), "v"(s[8*ks+5]));
            asm("v_cvt_pk_bf16_f32 %0, %1, %2" : "=v"(wD) : "v"(s[8*ks+6]), "v"(s[8*ks+7]));
            asm("v_permlane32_swap_b32 %0, %1" : "+v"(wA), "+v"(wC));
            asm("v_permlane32_swap_b32 %0, %1" : "+v"(wB), "+v"(wD));
            union { int w[4]; bf16x8 v; } u;
            u.w[0] = wA; u.w[1] = wB; u.w[2] = wC; u.w[3] = wD;
            pf[ks] = u.v;
        }
        *(bf16x8*)(sPex + (wm*4 + wk*2 + 0)*1024 + lane*16) = pf[0];
        *(bf16x8*)(sPex + (wm*4 + wk*2 + 1)*1024 + lane*16) = pf[1];
        if (lane < 32) sSt[(wave*2 + 1)*32 + lane] = tsum;

        // issue next-j K half-chunk 0 (in flight across exchange+PV)
        if (j + 1 < NJ) {
            krow += 64*DDIM;
            #pragma unroll
            for (int t = 0; t < 4; ++t) kf[0][t] = *(const bf16x8*)(krow + t*16);
        }
        BAR_LGKM();                                             // exchange 2
        float tsum_o = sSt[((wave^1)*2 + 1)*32 + l31];
        float alpha  = upd ? exp2f(m_r - mn) : 1.0f;
        l_r = l_r*alpha + (tsum + tsum_o);
        m_r = mn;
        if (__any(upd)) {               // rescale O (alpha indexed by q-row)
            #pragma unroll
            for (int r = 0; r < 16; ++r) {
                int row = (r&3) + 8*(r>>2) + 4*hi;
                float ar = __shfl(alpha, row);
                #pragma unroll
                for (int n = 0; n < 4; ++n) o[n][r] *= ar;
            }
        }

        // ---- PV: O[dv-half wk] += P(all 64 keys) * V^T; V windows from
        //      global (prefetch g+1 under g's MFMAs), P from regs/sPex ----
        const char* pb = sPex + wm*4096 + lane*16;
        #pragma unroll
        for (int g = 0; g < 4; ++g) {
            if (g < 3) {
                #pragma unroll
                for (int n = 0; n < 4; ++n)
                    vf[(g + 1) & 1][n] = *(const bf16x8*)(vrow
                        + (size_t)(n*32)*SKN + jtb + (g + 1)*16);
            }
            bf16x8 pa = ((g >> 1) == wk) ? pf[g & 1]
                        : *(const bf16x8*)(pb + g*1024);
            __builtin_amdgcn_s_setprio(1);
            #pragma unroll
            for (int n = 0; n < 4; ++n)
                o[n] = __builtin_amdgcn_mfma_f32_32x32x16_bf16(
                        pa, vf[g & 1][n], o[n], 0, 0, 0);
            __builtin_amdgcn_s_setprio(0);
        }
    }

    // ---- epilogue: shared (m,l) across wk; disjoint dv halves -> no merge ----
    const size_t base = (size_t)split * NROWS;
    const int gr0 = q0 + wm*32;
    if (wk == 0 && lane < 32) {
        Mpart[base + gr0 + lane] = m_r;     // log2 domain
        Lpart[base + gr0 + lane] = l_r;
    }
    #pragma unroll
    for (int r = 0; r < 16; ++r) {
        int row = (r&3) + 8*(r>>2) + 4*hi;
        float* orow = Opart + (base + gr0 + row) * (size_t)DVDIM + wk*128;
        #pragma unroll
        for (int n = 0; n < 4; ++n)
            orow[n*32 + l31] = o[n][r];
    }
}

// ---------------------------------------------------------------------------
// Combine NS split partials: out = sum_s(Os*ws) / sum_s(ls*ws), ws=2^(ms-M)
// (Mpart is log2-domain). grid = NROWS/4, block = 256. Coalesced.
// ---------------------------------------------------------------------------
__global__ void combine_splits(
    const float* __restrict__ Opart, const float* __restrict__ Mpart,
    const float* __restrict__ Lpart, float* __restrict__ out)
{
    const int row = blockIdx.x * 4 + (threadIdx.x >> 6);
    const int dv4 = (threadIdx.x & 63) * 4;
    float M = -1e30f;
    #pragma unroll
    for (int s = 0; s < NS; ++s) M = fmaxf(M, Mpart[(size_t)s*NROWS + row]);
    float denom = 0.f;
    float4 acc = make_float4(0.f, 0.f, 0.f, 0.f);
    #pragma unroll
    for (int s = 0; s < NS; ++s) {
        float w = exp2f(Mpart[(size_t)s*NROWS + row] - M);
        denom += Lpart[(size_t)s*NROWS + row] * w;
        float4 ov = *(const float4*)(Opart + ((size_t)s*NROWS + row)*DVDIM + dv4);
        acc.x += ov.x*w; acc.y += ov.y*w; acc.z += ov.z*w; acc.w += ov.w*w;
    }
    float inv = 1.0f / denom;
    *(float4*)(out + (size_t)row*DVDIM + dv4)
        = make_float4(acc.x*inv, acc.y*inv, acc.z*inv, acc.w*inv);
}

extern "C" void kernel_launch(void* const* d_in, const int* in_sizes, int n_in,
                              void* d_out, int out_size, void* d_ws, size_t ws_size,
                              hipStream_t stream) {
    const float* X  = (const float*)d_in[0];   // [8,2048,512]
    const float* Y  = (const float*)d_in[1];   // [4096,512]
    const float* Z  = (const float*)d_in[2];   // [4096,512]
    const float* Wk = (const float*)d_in[3];   // [512,512]
    const float* Wv = (const float*)d_in[4];   // [256,512]
    float* out = (float*)d_out;

    // workspace layout (~38.3 MB)
    char* ws = (char*)d_ws;
    unsigned short* keyb = (unsigned short*)ws;                    // 4 MB, natural [4096][512]
    unsigned short* vtb  = (unsigned short*)(ws + (4u<<20));       // 2 MB, natural [256][4096]
    float* Opart = (float*)(ws + (6u<<20));                        // NS x 16 MB
    float* Mpart = (float*)(ws + (6u<<20) + (size_t)NS*NROWS*DVDIM*4);
    float* Lpart = Mpart + (size_t)NS*NROWS;

    // both projections, one launch
    proj_gemms<<<dim3(64, 8, 2), dim3(256), 0, stream>>>(Y, Z, Wk, Wv, keyb, vtb);
    // fused attention: 256 blocks (1/CU), 8 waves, K/V direct-to-register
    attn_fused<<<dim3(256), dim3(512), 0, stream>>>(
        X, keyb, vtb, Opart, Mpart, Lpart);
    // merge splits
    combine_splits<<<dim3(NROWS/4), dim3(256), 0, stream>>>(Opart, Mpart, Lpart, out);
}

// Round 7
// 471.180 us; speedup vs baseline: 1.0145x; 1.0145x over previous
//
#include <hip/hip_runtime.h>
#include <hip/hip_bf16.h>

// Problem constants
#define NB    8
#define SQN   2048
#define SKN   4096
#define DDIM  512
#define DVDIM 256
#define NROWS (NB*SQN)      // 16384
#define NS    2             // SK splits
#define NJ    ((SKN/64)/NS) // 32 j-iterations per split (64 keys each)

typedef __attribute__((ext_vector_type(8)))  short bf16x8;   // 8 bf16 = 4 VGPRs (MFMA A/B frag)
typedef __attribute__((ext_vector_type(4)))  short bf16x4;
typedef __attribute__((ext_vector_type(4)))  float f32x4;    // 16x16 MFMA C/D frag
typedef __attribute__((ext_vector_type(16))) float f32x16;   // 32x32 MFMA C/D frag

// fp32 -> bf16 round-to-nearest-even, bit pattern as short
__device__ __forceinline__ short f2bf(float f) {
    unsigned u = __float_as_uint(f);
    return (short)((u + 0x7FFFu + ((u >> 16) & 1u)) >> 16);
}

// LDS-only barrier: vm loads (K/V register prefetches) stay in flight.
// waitcnt BEFORE barrier (producer side); sched_barrier fences per rule #18.
#define BAR_LGKM() do {                                                       \
    asm volatile("s_waitcnt lgkmcnt(0)" ::: "memory");                        \
    __builtin_amdgcn_sched_barrier(0);                                        \
    __builtin_amdgcn_s_barrier();                                             \
    __builtin_amdgcn_sched_barrier(0);                                        \
} while (0)

// ---------------------------------------------------------------------------
// Fused projection GEMMs, one launch. grid = (64, 8, 2).  (unchanged)
//  z=0: key[s][d]  = sum_c Y[s][c]*Wk[d][c]   M=4096 N=512
//  z=1: vt[dv][s]  = sum_c Wv[dv][c]*Z[s][c]  M=256  N=4096 (uses 256 of 512 tiles)
// ---------------------------------------------------------------------------
__global__ __launch_bounds__(256, 2) void proj_gemms(
    const float* __restrict__ Y, const float* __restrict__ Z,
    const float* __restrict__ Wk, const float* __restrict__ Wv,
    unsigned short* __restrict__ keyb, unsigned short* __restrict__ vtb)
{
    __shared__ short sA[64*128];   // 16 KB
    __shared__ short sB[64*128];   // 16 KB
    const float *A, *Bm;
    unsigned short* C;
    int N, m0, n0;
    if (blockIdx.z == 0) {
        A = Y; Bm = Wk; C = keyb; N = DDIM;
        m0 = blockIdx.x * 64; n0 = blockIdx.y * 64;
    } else {
        int lin = blockIdx.x * 8 + blockIdx.y;
        if (lin >= 256) return;                 // value GEMM needs 256 tiles
        A = Wv; Bm = Z; C = vtb; N = SKN;
        m0 = (lin >> 6) * 64; n0 = (lin & 63) * 64;
    }
    const int tid  = threadIdx.x;
    const int wave = tid >> 6;
    const int lane = tid & 63;
    const int quad = lane >> 4;
    const int l15  = lane & 15;

    f32x4 acc[4];
    #pragma unroll
    for (int n = 0; n < 4; ++n) { acc[n][0]=0.f; acc[n][1]=0.f; acc[n][2]=0.f; acc[n][3]=0.f; }

    float4 ra[8], rb[8];
    #pragma unroll
    for (int it = 0; it < 8; ++it) {            // prefetch kc=0
        int f = it*1024 + tid*4, row = f >> 7, col = f & 127;
        ra[it] = *(const float4*)(A  + (size_t)(m0+row)*DDIM + col);
        rb[it] = *(const float4*)(Bm + (size_t)(n0+row)*DDIM + col);
    }

    for (int kc = 0; kc < DDIM; kc += 128) {
        __syncthreads();                        // LDS free (prev MFMA done)
        #pragma unroll
        for (int it = 0; it < 8; ++it) {
            int f = it*1024 + tid*4;
            bf16x4 a4; a4[0]=f2bf(ra[it].x); a4[1]=f2bf(ra[it].y); a4[2]=f2bf(ra[it].z); a4[3]=f2bf(ra[it].w);
            *(bf16x4*)(sA + f) = a4;
            bf16x4 b4; b4[0]=f2bf(rb[it].x); b4[1]=f2bf(rb[it].y); b4[2]=f2bf(rb[it].z); b4[3]=f2bf(rb[it].w);
            *(bf16x4*)(sB + f) = b4;
        }
        __syncthreads();                        // staged visible
        if (kc + 128 < DDIM) {                  // prefetch kc+1 (in flight under MFMA)
            #pragma unroll
            for (int it = 0; it < 8; ++it) {
                int f = it*1024 + tid*4, row = f >> 7, col = f & 127;
                ra[it] = *(const float4*)(A  + (size_t)(m0+row)*DDIM + kc + 128 + col);
                rb[it] = *(const float4*)(Bm + (size_t)(n0+row)*DDIM + kc + 128 + col);
            }
        }
        #pragma unroll
        for (int t = 0; t < 4; ++t) {
            bf16x8 af = *(const bf16x8*)(sA + (wave*16 + l15)*128 + t*32 + quad*8);
            #pragma unroll
            for (int n = 0; n < 4; ++n) {
                bf16x8 bfr = *(const bf16x8*)(sB + (n*16 + l15)*128 + t*32 + quad*8);
                acc[n] = __builtin_amdgcn_mfma_f32_16x16x32_bf16(af, bfr, acc[n], 0, 0, 0);
            }
        }
    }
    #pragma unroll
    for (int n = 0; n < 4; ++n)
        #pragma unroll
        for (int r = 0; r < 4; ++r) {
            int m  = m0 + wave*16 + quad*4 + r;
            int nn = n0 + n*16 + l15;
            C[(size_t)m*N + nn] = (unsigned short)f2bf(acc[n][r]);
        }
}

// ---------------------------------------------------------------------------
// Fused attention, R7: Q lives WHOLLY IN LDS (frag-linear, written once at
// prologue, shared by each wk pair). R6 post-mortem: gfx950 splits the
// 256-reg/wave unified budget into 128 arch VGPR + 128 AGPR when MFMA is
// present (VGPR_Count pinned at 128 every round); Q-stationary-in-regs
// (128 VGPR) forced scratch/AGPR spill in every prior variant. With Q in
// LDS: arch ~112 VGPR (kf32+vf32+pf8+s16+temps), AGPR 80 (o64+s16) -> NO
// spill of any kind. QK reads Q via conflict-free lane-linear ds_read_b128
// (4 per half-chunk, hidden under the 4 MFMAs).
// K/V stream GLOBAL -> REGISTERS (frag = 16 contiguous B/lane, natural
// layout); LDS = Q (128 KB) + P/stat exchange (18 KB) = 149.5 KB, 1
// block/CU, 8 waves (wm=0..3 x wk=0..1). 2 lgkm-only barriers/j; waves
// free-run (no staging barriers). XCD-split swizzle keeps K/V L2-resident.
// T13 defer-max log2-domain softmax (verified R6); Mpart log2-domain.
// ---------------------------------------------------------------------------
__global__ __launch_bounds__(512, 2) void attn_fused(
    const float* __restrict__ X,            // [16384][512] fp32
    const unsigned short* __restrict__ Kb,  // key bf16 [4096][512] natural
    const unsigned short* __restrict__ Vt,  // V^T bf16 [256][4096] natural
    float* __restrict__ Opart,              // [NS][16384][256]
    float* __restrict__ Mpart,              // [NS][16384] (log2 domain)
    float* __restrict__ Lpart)              // [NS][16384]
{
    // 0      : sQ 128KB: [wm=4][tile=32][lane]x16B  (tile t2 = Q B-frag for
    //          k-step t2: elem e = X[q0+wm*32+l31][t2*16 + hi*8 + e]*scale)
    // 131072 : sPex 16KB [wm=4][g=4][lane]x16B P A-frags
    // 147456 : sSt 2KB [wave=8][slot=2][32] floats
    __shared__ __align__(16) char smem[149504];
    char* sPex = smem + 131072;
    float* sSt = (float*)(smem + 147456);

    const int tid  = threadIdx.x;
    const int wave = tid >> 6;      // 0..7
    const int lane = tid & 63;
    const int l31  = lane & 31;
    const int hi   = lane >> 5;
    const int wm   = wave >> 1;     // 0..3: Q-row group
    const int wk   = wave & 1;      // key-half for QK / dv-half for PV

    // XCD-split swizzle: bid&7 = XCD; XCD 0-3 -> split 0, 4-7 -> split 1.
    const int bid   = blockIdx.x;          // 0..255
    const int xcd   = bid & 7;
    const int slot  = bid >> 3;            // 0..31
    const int split = xcd >> 2;
    const int q0    = ((xcd & 3)*32 + slot) * 128;
    // 1/sqrt(512) * log2(e): softmax runs in log2 domain (exp2)
    const float scale = 0.04419417382415922f * 1.4426950408889634f;

    // ---- prologue: write this wm-group's Q frags to LDS (wk pair splits
    //      the 32 tiles; each wave: 32 float4 loads + 16 ds_write_b128) ----
    {
        const float* xrow = X + (size_t)(q0 + wm*32 + l31)*DDIM + hi*8;
        char* qbase = smem + wm*32768;
        #pragma unroll
        for (int i = 0; i < 16; ++i) {
            const int t2 = wk*16 + i;
            float4 a = *(const float4*)(xrow + t2*16);
            float4 b = *(const float4*)(xrow + t2*16 + 4);
            bf16x8 q;
            q[0]=f2bf(a.x*scale); q[1]=f2bf(a.y*scale); q[2]=f2bf(a.z*scale); q[3]=f2bf(a.w*scale);
            q[4]=f2bf(b.x*scale); q[5]=f2bf(b.y*scale); q[6]=f2bf(b.z*scale); q[7]=f2bf(b.w*scale);
            *(bf16x8*)(qbase + t2*1024 + lane*16) = q;
        }
    }

    // O acc: D[row=q][col=dv], wave's dv-half = wk*128 + n*32 + l31. 64 AGPR.
    f32x16 o[4];
    #pragma unroll
    for (int n = 0; n < 4; ++n)
        #pragma unroll
        for (int r = 0; r < 16; ++r) o[n][r] = 0.f;
    float m_r = -1e30f, l_r = 0.f;       // shared across wk pair (identical by induction)

    const int jt0 = split * (NJ*64);

    // K frag stream: lane reads K[jtb + wk*32 + l31][col .. col+7], 16B.
    const unsigned short* krow = Kb + (size_t)(jt0 + wk*32 + l31)*DDIM + hi*8;
    // V frag stream: col = dv = wk*128 + n*32 + l31, k = g*16 + hi*8.
    const unsigned short* vrow = Vt + (size_t)(wk*128 + l31)*SKN + hi*8;

    bf16x8 kf[2][4];                    // QK half-chunk double buffer (32 VGPR)
    bf16x8 vf[2][4];                    // PV window double buffer (32 VGPR)

    BAR_LGKM();                         // Q visible to the wk pair

    // prologue: load j=0 half-chunk 0
    #pragma unroll
    for (int t = 0; t < 4; ++t) kf[0][t] = *(const bf16x8*)(krow + t*16);

    const char* qb = smem + wm*32768 + lane*16;   // Q frag read base

    for (int j = 0; j < NJ; ++j) {
        const int jtb = jt0 + j*64;
        f32x16 s;                       // P^T acc: D[row=key][col=q]
        #pragma unroll
        for (int r = 0; r < 16; ++r) s[r] = 0.f;

        // ---- QK: 8 half-chunks of 64 d; prefetch K(h+1) while computing h;
        //      Q frags from LDS (lane-linear ds_read_b128, conflict-free) ----
        #pragma unroll
        for (int h = 0; h < 8; ++h) {
            if (h < 7) {
                const unsigned short* ka = krow + (h + 1)*64;
                #pragma unroll
                for (int t = 0; t < 4; ++t)
                    kf[(h + 1) & 1][t] = *(const bf16x8*)(ka + t*16);
            }
            __builtin_amdgcn_s_setprio(1);
            #pragma unroll
            for (int t = 0; t < 4; ++t) {
                bf16x8 qv = *(const bf16x8*)(qb + (h*4 + t)*1024);
                s = __builtin_amdgcn_mfma_f32_32x32x16_bf16(
                        kf[h & 1][t], qv, s, 0, 0, 0);
            }
            __builtin_amdgcn_s_setprio(0);
        }

        // issue V window g=0 now: latency hides under softmax
        #pragma unroll
        for (int n = 0; n < 4; ++n)
            vf[0][n] = *(const bf16x8*)(vrow + (size_t)(n*32)*SKN + jtb);

        // ---- softmax (log2 domain), in-lane; joint max across wk pair ----
        float tmax = fmaxf(fmaxf(fmaxf(s[0],s[1]),fmaxf(s[2],s[3])),
                           fmaxf(fmaxf(s[4],s[5]),fmaxf(s[6],s[7])));
        tmax = fmaxf(tmax, fmaxf(fmaxf(fmaxf(s[8],s[9]),fmaxf(s[10],s[11])),
                                 fmaxf(fmaxf(s[12],s[13]),fmaxf(s[14],s[15]))));
        tmax = fmaxf(tmax, __shfl_xor(tmax, 32));
        if (lane < 32) sSt[(wave*2 + 0)*32 + lane] = tmax;
        BAR_LGKM();                                             // exchange 1
        float tmax_o = sSt[((wave^1)*2 + 0)*32 + l31];
        const float tj   = fmaxf(tmax, tmax_o);
        // T13 defer-max: only move the reference when it grew by >8 (p <= 2^8)
        const bool  upd  = tj > m_r + 8.0f;
        const float mn   = upd ? tj : m_r;
        float tsum = 0.f;
        #pragma unroll
        for (int r = 0; r < 16; ++r) { float pv = exp2f(s[r] - mn); s[r] = pv; tsum += pv; }
        tsum += __shfl_xor(tsum, 32);

        // P -> PV A-frags in-register (cvt_pk + permlane32_swap, proven R1-R6)
        bf16x8 pf[2];
        #pragma unroll
        for (int ks = 0; ks < 2; ++ks) {
            int wA, wB, wC, wD;
            asm("v_cvt_pk_bf16_f32 %0, %1, %2" : "=v"(wA) : "v"(s[8*ks+0]), "v"(s[8*ks+1]));
            asm("v_cvt_pk_bf16_f32 %0, %1, %2" : "=v"(wB) : "v"(s[8*ks+2]), "v"(s[8*ks+3]));
            asm("v_cvt_pk_bf16_f32 %0, %1, %2" : "=v"(wC) : "v"(s[8*ks+4]), "v"(s[8*ks+5]));
            asm("v_cvt_pk_bf16_f32 %0, %1, %2" : "=v"(wD) : "v"(s[8*ks+6]), "v"(s[8*ks+7]));
            asm("v_permlane32_swap_b32 %0, %1" : "+v"(wA), "+v"(wC));
            asm("v_permlane32_swap_b32 %0, %1" : "+v"(wB), "+v"(wD));
            union { int w[4]; bf16x8 v; } u;
            u.w[0] = wA; u.w[1] = wB; u.w[2] = wC; u.w[3] = wD;
            pf[ks] = u.v;
        }
        *(bf16x8*)(sPex + (wm*4 + wk*2 + 0)*1024 + lane*16) = pf[0];
        *(bf16x8*)(sPex + (wm*4 + wk*2 + 1)*1024 + lane*16) = pf[1];
        if (lane < 32) sSt[(wave*2 + 1)*32 + lane] = tsum;

        // issue next-j K half-chunk 0 (in flight across exchange+PV)
        if (j + 1 < NJ) {
            krow += 64*DDIM;
            #pragma unroll
            for (int t = 0; t < 4; ++t) kf[0][t] = *(const bf16x8*)(krow + t*16);
        }
        BAR_LGKM();                                             // exchange 2
        float tsum_o = sSt[((wave^1)*2 + 1)*32 + l31];
        float alpha  = upd ? exp2f(m_r - mn) : 1.0f;
        l_r = l_r*alpha + (tsum + tsum_o);
        m_r = mn;
        if (__any(upd)) {               // rescale O (alpha indexed by q-row)
            #pragma unroll
            for (int r = 0; r < 16; ++r) {
                int row = (r&3) + 8*(r>>2) + 4*hi;
                float ar = __shfl(alpha, row);
                #pragma unroll
                for (int n = 0; n < 4; ++n) o[n][r] *= ar;
            }
        }

        // ---- PV: O[dv-half wk] += P(all 64 keys) * V^T; V windows from
        //      global (prefetch g+1 under g's MFMAs), P from regs/sPex ----
        const char* pb = sPex + wm*4096 + lane*16;
        #pragma unroll
        for (int g = 0; g < 4; ++g) {
            if (g < 3) {
                #pragma unroll
                for (int n = 0; n < 4; ++n)
                    vf[(g + 1) & 1][n] = *(const bf16x8*)(vrow
                        + (size_t)(n*32)*SKN + jtb + (g + 1)*16);
            }
            bf16x8 pa = ((g >> 1) == wk) ? pf[g & 1]
                        : *(const bf16x8*)(pb + g*1024);
            __builtin_amdgcn_s_setprio(1);
            #pragma unroll
            for (int n = 0; n < 4; ++n)
                o[n] = __builtin_amdgcn_mfma_f32_32x32x16_bf16(
                        pa, vf[g & 1][n], o[n], 0, 0, 0);
            __builtin_amdgcn_s_setprio(0);
        }
    }

    // ---- epilogue: shared (m,l) across wk; disjoint dv halves -> no merge ----
    const size_t base = (size_t)split * NROWS;
    const int gr0 = q0 + wm*32;
    if (wk == 0 && lane < 32) {
        Mpart[base + gr0 + lane] = m_r;     // log2 domain
        Lpart[base + gr0 + lane] = l_r;
    }
    #pragma unroll
    for (int r = 0; r < 16; ++r) {
        int row = (r&3) + 8*(r>>2) + 4*hi;
        float* orow = Opart + (base + gr0 + row) * (size_t)DVDIM + wk*128;
        #pragma unroll
        for (int n = 0; n < 4; ++n)
            orow[n*32 + l31] = o[n][r];
    }
}

// ---------------------------------------------------------------------------
// Combine NS split partials: out = sum_s(Os*ws) / sum_s(ls*ws), ws=2^(ms-M)
// (Mpart is log2-domain). grid = NROWS/4, block = 256. Coalesced.
// ---------------------------------------------------------------------------
__global__ void combine_splits(
    const float* __restrict__ Opart, const float* __restrict__ Mpart,
    const float* __restrict__ Lpart, float* __restrict__ out)
{
    const int row = blockIdx.x * 4 + (threadIdx.x >> 6);
    const int dv4 = (threadIdx.x & 63) * 4;
    float M = -1e30f;
    #pragma unroll
    for (int s = 0; s < NS; ++s) M = fmaxf(M, Mpart[(size_t)s*NROWS + row]);
    float denom = 0.f;
    float4 acc = make_float4(0.f, 0.f, 0.f, 0.f);
    #pragma unroll
    for (int s = 0; s < NS; ++s) {
        float w = exp2f(Mpart[(size_t)s*NROWS + row] - M);
        denom += Lpart[(size_t)s*NROWS + row] * w;
        float4 ov = *(const float4*)(Opart + ((size_t)s*NROWS + row)*DVDIM + dv4);
        acc.x += ov.x*w; acc.y += ov.y*w; acc.z += ov.z*w; acc.w += ov.w*w;
    }
    float inv = 1.0f / denom;
    *(float4*)(out + (size_t)row*DVDIM + dv4)
        = make_float4(acc.x*inv, acc.y*inv, acc.z*inv, acc.w*inv);
}

extern "C" void kernel_launch(void* const* d_in, const int* in_sizes, int n_in,
                              void* d_out, int out_size, void* d_ws, size_t ws_size,
                              hipStream_t stream) {
    const float* X  = (const float*)d_in[0];   // [8,2048,512]
    const float* Y  = (const float*)d_in[1];   // [4096,512]
    const float* Z  = (const float*)d_in[2];   // [4096,512]
    const float* Wk = (const float*)d_in[3];   // [512,512]
    const float* Wv = (const float*)d_in[4];   // [256,512]
    float* out = (float*)d_out;

    // workspace layout (~38.3 MB)
    char* ws = (char*)d_ws;
    unsigned short* keyb = (unsigned short*)ws;                    // 4 MB, natural [4096][512]
    unsigned short* vtb  = (unsigned short*)(ws + (4u<<20));       // 2 MB, natural [256][4096]
    float* Opart = (float*)(ws + (6u<<20));                        // NS x 16 MB
    float* Mpart = (float*)(ws + (6u<<20) + (size_t)NS*NROWS*DVDIM*4);
    float* Lpart = Mpart + (size_t)NS*NROWS;

    // both projections, one launch
    proj_gemms<<<dim3(64, 8, 2), dim3(256), 0, stream>>>(Y, Z, Wk, Wv, keyb, vtb);
    // fused attention: 256 blocks (1/CU), 8 waves, Q-in-LDS + K/V-to-register
    attn_fused<<<dim3(256), dim3(512), 0, stream>>>(
        X, keyb, vtb, Opart, Mpart, Lpart);
    // merge splits
    combine_splits<<<dim3(NROWS/4), dim3(256), 0, stream>>>(Opart, Mpart, Lpart, out);
}

// Round 8
// 252.922 us; speedup vs baseline: 1.8899x; 1.8629x over previous
//
#include <hip/hip_runtime.h>
#include <hip/hip_bf16.h>

// Problem constants
#define NB    8
#define SQN   2048
#define SKN   4096
#define DDIM  512
#define DVDIM 256
#define NROWS (NB*SQN)      // 16384
#define NS    2             // SK splits
#define NJ    ((SKN/64)/NS) // 32 j-iterations per split (64 keys each)

typedef __attribute__((ext_vector_type(8)))  short bf16x8;   // 8 bf16 = 4 VGPRs (MFMA A/B frag)
typedef __attribute__((ext_vector_type(4)))  short bf16x4;
typedef __attribute__((ext_vector_type(4)))  float f32x4;    // 16x16 MFMA C/D frag
typedef __attribute__((ext_vector_type(16))) float f32x16;   // 32x32 MFMA C/D frag

// fp32 -> bf16 round-to-nearest-even, bit pattern as short
__device__ __forceinline__ short f2bf(float f) {
    unsigned u = __float_as_uint(f);
    return (short)((u + 0x7FFFu + ((u >> 16) & 1u)) >> 16);
}

// LDS-only barrier: vm loads (K/V register prefetches) stay in flight.
// sched_barrier fences per rule #18 (no hoisting across the asm wait).
#define BAR_LGKM() do {                                                       \
    asm volatile("s_waitcnt lgkmcnt(0)" ::: "memory");                        \
    __builtin_amdgcn_sched_barrier(0);                                        \
    __builtin_amdgcn_s_barrier();                                             \
    __builtin_amdgcn_sched_barrier(0);                                        \
} while (0)

// ---------------------------------------------------------------------------
// Fused projection GEMMs, one launch. grid = (64, 8, 2).
//  z=0: key[s][d]  = sum_c Y[s][c]*Wk[d][c]   M=4096 N=512
//  z=1: vt[dv][s]  = sum_c Wv[dv][c]*Z[s][c]  M=256  N=4096 (uses 256 of 512 tiles)
// R8: epilogues write K/V PRE-PACKED in fragment-lane order so the attention
// kernel's K/V loads are fully-coalesced 1KB wave-loads straight to regs
// (R7 post-mortem: 32-line divergent gathers serialized the L1, 29k cyc/j).
// Packed layouts (16B units; lane = hi*32 + l31):
//  K: tile ((J*4+c)*8+tp)*2+kh holds K[J*64+kh*32+l31][c*128+tp*16+hi*8+..7]
//  V: tile (J*8+wv*4+n2)*4+g   holds V^T[wv*128+n2*32+l31][J*64+g*16+hi*8+..7]
// ---------------------------------------------------------------------------
__global__ __launch_bounds__(256, 2) void proj_gemms(
    const float* __restrict__ Y, const float* __restrict__ Z,
    const float* __restrict__ Wk, const float* __restrict__ Wv,
    unsigned short* __restrict__ keyb, unsigned short* __restrict__ vtb)
{
    __shared__ short sA[64*128];   // 16 KB
    __shared__ short sB[64*128];   // 16 KB
    const float *A, *Bm;
    unsigned short* C;
    int m0, n0;
    const bool kpath = (blockIdx.z == 0);
    if (kpath) {
        A = Y; Bm = Wk; C = keyb;
        m0 = blockIdx.x * 64; n0 = blockIdx.y * 64;
    } else {
        int lin = blockIdx.x * 8 + blockIdx.y;
        if (lin >= 256) return;                 // value GEMM needs 256 tiles
        A = Wv; Bm = Z; C = vtb;
        m0 = (lin >> 6) * 64; n0 = (lin & 63) * 64;
    }
    const int tid  = threadIdx.x;
    const int wave = tid >> 6;
    const int lane = tid & 63;
    const int quad = lane >> 4;
    const int l15  = lane & 15;

    f32x4 acc[4];
    #pragma unroll
    for (int n = 0; n < 4; ++n) { acc[n][0]=0.f; acc[n][1]=0.f; acc[n][2]=0.f; acc[n][3]=0.f; }

    float4 ra[8], rb[8];
    #pragma unroll
    for (int it = 0; it < 8; ++it) {            // prefetch kc=0
        int f = it*1024 + tid*4, row = f >> 7, col = f & 127;
        ra[it] = *(const float4*)(A  + (size_t)(m0+row)*DDIM + col);
        rb[it] = *(const float4*)(Bm + (size_t)(n0+row)*DDIM + col);
    }

    for (int kc = 0; kc < DDIM; kc += 128) {
        __syncthreads();                        // LDS free (prev MFMA done)
        #pragma unroll
        for (int it = 0; it < 8; ++it) {
            int f = it*1024 + tid*4;
            bf16x4 a4; a4[0]=f2bf(ra[it].x); a4[1]=f2bf(ra[it].y); a4[2]=f2bf(ra[it].z); a4[3]=f2bf(ra[it].w);
            *(bf16x4*)(sA + f) = a4;
            bf16x4 b4; b4[0]=f2bf(rb[it].x); b4[1]=f2bf(rb[it].y); b4[2]=f2bf(rb[it].z); b4[3]=f2bf(rb[it].w);
            *(bf16x4*)(sB + f) = b4;
        }
        __syncthreads();                        // staged visible
        if (kc + 128 < DDIM) {                  // prefetch kc+1 (in flight under MFMA)
            #pragma unroll
            for (int it = 0; it < 8; ++it) {
                int f = it*1024 + tid*4, row = f >> 7, col = f & 127;
                ra[it] = *(const float4*)(A  + (size_t)(m0+row)*DDIM + kc + 128 + col);
                rb[it] = *(const float4*)(Bm + (size_t)(n0+row)*DDIM + kc + 128 + col);
            }
        }
        #pragma unroll
        for (int t = 0; t < 4; ++t) {
            bf16x8 af = *(const bf16x8*)(sA + (wave*16 + l15)*128 + t*32 + quad*8);
            #pragma unroll
            for (int n = 0; n < 4; ++n) {
                bf16x8 bfr = *(const bf16x8*)(sB + (n*16 + l15)*128 + t*32 + quad*8);
                acc[n] = __builtin_amdgcn_mfma_f32_16x16x32_bf16(af, bfr, acc[n], 0, 0, 0);
            }
        }
    }
    // packed epilogue
    #pragma unroll
    for (int n = 0; n < 4; ++n)
        #pragma unroll
        for (int r = 0; r < 4; ++r) {
            int m  = m0 + wave*16 + quad*4 + r;
            int nn = n0 + n*16 + l15;
            unsigned short v = (unsigned short)f2bf(acc[n][r]);
            size_t off;
            if (kpath) {        // s=m (key row), d=nn
                int J = m >> 6, kh = (m >> 5) & 1, ls = m & 31;
                int c = nn >> 7, tp = (nn >> 4) & 7, hd = (nn >> 3) & 1, d7 = nn & 7;
                off = (size_t)(((J*4 + c)*8 + tp)*2 + kh)*512 + (hd*32 + ls)*8 + d7;
            } else {            // dv=m, key=nn
                int J = nn >> 6, g = (nn >> 4) & 3, hk = (nn >> 3) & 1, k7 = nn & 7;
                int wv = m >> 7, n2 = (m >> 5) & 3, lv = m & 31;
                off = (size_t)((J*8 + wv*4 + n2)*4 + g)*512 + (hk*32 + lv)*8 + k7;
            }
            C[off] = v;
        }
}

// ---------------------------------------------------------------------------
// Fused attention, R8: K/V fragments load from PRE-PACKED DRAM as coalesced
// 1KB wave-loads straight to registers (each lane's 16B frag is at
// tile_base + lane*16). No LDS staging, no staging barriers, no divergence.
// Block = 128 threads = ONE wk pair for 32 Q-rows; grid = 1024 (4 blocks/CU)
// -> maximal wave desync, exchange barriers sync only 2 waves.
// Q in LDS (32 KB/block, R7-proven; keeps arch VGPRs low). kf: depth-2
// triple-buffer ring (issue h+2 at phase h). vf: 2 buffers, g0/g1 issued
// under QK h=6/7, g2/g3 issued during PV. LDS: Q 32KB + sPex 4KB + sSt 0.5KB.
// XCD-split swizzle (split = xcd>>2) keeps each XCD's K+V (3MB) L2-resident.
// T13 defer-max log2-domain softmax (verified R6/R7); Mpart log2-domain.
// ---------------------------------------------------------------------------
__global__ __launch_bounds__(128, 2) void attn_fused(
    const float* __restrict__ X,            // [16384][512] fp32
    const unsigned short* __restrict__ Kb,  // key bf16, PACKED (4 MB)
    const unsigned short* __restrict__ Vt,  // V^T bf16, PACKED (2 MB)
    float* __restrict__ Opart,              // [NS][16384][256]
    float* __restrict__ Mpart,              // [NS][16384] (log2 domain)
    float* __restrict__ Lpart)              // [NS][16384]
{
    // 0     : sQ 32KB [t2=32][lane]x16B  (Q B-frag tile t2: elem e =
    //         X[q0+l31][t2*16 + hi*8 + e]*scale)
    // 32768 : sPex 4KB [wk*2+ks][lane]x16B P A-frags
    // 36864 : sSt 512B [wk*2+slot][32] floats
    __shared__ __align__(16) char smem[37376];
    char* sQ   = smem;
    char* sPex = smem + 32768;
    float* sSt = (float*)(smem + 36864);

    const int tid  = threadIdx.x;
    const int wk   = tid >> 6;      // 0..1: key-half for QK / dv-half for PV
    const int lane = tid & 63;
    const int l31  = lane & 31;
    const int hi   = lane >> 5;

    // XCD-split swizzle: bid&7 = XCD; XCD 0-3 -> split 0, 4-7 -> split 1.
    const int bid   = blockIdx.x;          // 0..1023
    const int xcd   = bid & 7;
    const int slot  = bid >> 3;            // 0..127
    const int split = xcd >> 2;
    const int q0    = ((xcd & 3)*128 + slot) * 32;
    // 1/sqrt(512) * log2(e): softmax runs in log2 domain (exp2)
    const float scale = 0.04419417382415922f * 1.4426950408889634f;

    // ---- prologue: stage this block's 32 Q frag-tiles to LDS (wk splits) ----
    {
        const float* xrow = X + (size_t)(q0 + l31)*DDIM + hi*8;
        #pragma unroll
        for (int i = 0; i < 16; ++i) {
            const int t2 = wk*16 + i;
            float4 a = *(const float4*)(xrow + t2*16);
            float4 b = *(const float4*)(xrow + t2*16 + 4);
            bf16x8 q;
            q[0]=f2bf(a.x*scale); q[1]=f2bf(a.y*scale); q[2]=f2bf(a.z*scale); q[3]=f2bf(a.w*scale);
            q[4]=f2bf(b.x*scale); q[5]=f2bf(b.y*scale); q[6]=f2bf(b.z*scale); q[7]=f2bf(b.w*scale);
            *(bf16x8*)(sQ + t2*1024 + lane*16) = q;
        }
    }

    // O acc: D[row=q][col=dv], wave's dv-half = wk*128 + n*32 + l31.
    f32x16 o[4];
    #pragma unroll
    for (int n = 0; n < 4; ++n)
        #pragma unroll
        for (int r = 0; r < 16; ++r) o[n][r] = 0.f;
    float m_r = -1e30f, l_r = 0.f;       // shared across wk pair

    // packed base pointers (this wave's key-half / dv-half, lane folded in)
    const int Jg0 = split * NJ;
    const char* kp = (const char*)Kb + (size_t)Jg0*65536 + wk*1024 + lane*16;
    const char* vp = (const char*)Vt + (size_t)Jg0*32768 + wk*16384 + lane*16;
    // K frag (h,t): kp + (h>>1)*16384 + (((h&1)*4+t)*2)*1024
    // V frag (n,g): vp + n*4096 + g*1024
    #define KOFF(h_, t_) ((size_t)((h_)>>1)*16384 + (size_t)((((h_)&1)*4 + (t_))*2)*1024)

    bf16x8 kf[3][4];                    // depth-2 ring (48 VGPR)
    bf16x8 vf[2][4];                    // PV double buffer (32 VGPR)

    BAR_LGKM();                         // Q visible to the pair

    // prologue loads: j=0 half-chunks 0,1 -> buf0, buf1
    #pragma unroll
    for (int t = 0; t < 4; ++t) kf[0][t] = *(const bf16x8*)(kp + KOFF(0, t));
    #pragma unroll
    for (int t = 0; t < 4; ++t) kf[1][t] = *(const bf16x8*)(kp + KOFF(1, t));

    const char* qb = sQ + lane*16;

    for (int j = 0; j < NJ; ++j) {
        f32x16 s;                       // P^T acc: D[row=key][col=q]
        #pragma unroll
        for (int r = 0; r < 16; ++r) s[r] = 0.f;

        // ---- QK: 8 phases; issue kf(h+2) at phase h (depth-2); V g0/g1
        //      issued at phases 6/7 (drain under softmax) ----
        #pragma unroll
        for (int h = 0; h < 8; ++h) {
            if (h < 6) {
                #pragma unroll
                for (int t = 0; t < 4; ++t)
                    kf[(h + 2) % 3][t] = *(const bf16x8*)(kp + KOFF(h + 2, t));
            } else {
                const int g = h - 6;    // V windows g=0,1
                #pragma unroll
                for (int n = 0; n < 4; ++n)
                    vf[g][n] = *(const bf16x8*)(vp + n*4096 + g*1024);
            }
            __builtin_amdgcn_s_setprio(1);
            #pragma unroll
            for (int t = 0; t < 4; ++t) {
                bf16x8 qv = *(const bf16x8*)(qb + (h*4 + t)*1024);
                s = __builtin_amdgcn_mfma_f32_32x32x16_bf16(
                        kf[h % 3][t], qv, s, 0, 0, 0);
            }
            __builtin_amdgcn_s_setprio(0);
        }

        // ---- softmax (log2 domain), in-lane; joint max across wk pair ----
        float tmax = fmaxf(fmaxf(fmaxf(s[0],s[1]),fmaxf(s[2],s[3])),
                           fmaxf(fmaxf(s[4],s[5]),fmaxf(s[6],s[7])));
        tmax = fmaxf(tmax, fmaxf(fmaxf(fmaxf(s[8],s[9]),fmaxf(s[10],s[11])),
                                 fmaxf(fmaxf(s[12],s[13]),fmaxf(s[14],s[15]))));
        tmax = fmaxf(tmax, __shfl_xor(tmax, 32));
        if (lane < 32) sSt[(wk*2 + 0)*32 + lane] = tmax;
        BAR_LGKM();                                             // exchange 1
        float tmax_o = sSt[((wk^1)*2 + 0)*32 + l31];
        const float tj   = fmaxf(tmax, tmax_o);
        // T13 defer-max: only move the reference when it grew by >8 (p <= 2^8)
        const bool  upd  = tj > m_r + 8.0f;
        const float mn   = upd ? tj : m_r;
        float tsum = 0.f;
        #pragma unroll
        for (int r = 0; r < 16; ++r) { float pv = exp2f(s[r] - mn); s[r] = pv; tsum += pv; }
        tsum += __shfl_xor(tsum, 32);

        // P -> PV A-frags in-register (cvt_pk + permlane32_swap, proven R1-R7)
        bf16x8 pf[2];
        #pragma unroll
        for (int ks = 0; ks < 2; ++ks) {
            int wA, wB, wC, wD;
            asm("v_cvt_pk_bf16_f32 %0, %1, %2" : "=v"(wA) : "v"(s[8*ks+0]), "v"(s[8*ks+1]));
            asm("v_cvt_pk_bf16_f32 %0, %1, %2" : "=v"(wB) : "v"(s[8*ks+2]), "v"(s[8*ks+3]));
            asm("v_cvt_pk_bf16_f32 %0, %1, %2" : "=v"(wC) : "v"(s[8*ks+4]), "v"(s[8*ks+5]));
            asm("v_cvt_pk_bf16_f32 %0, %1, %2" : "=v"(wD) : "v"(s[8*ks+6]), "v"(s[8*ks+7]));
            asm("v_permlane32_swap_b32 %0, %1" : "+v"(wA), "+v"(wC));
            asm("v_permlane32_swap_b32 %0, %1" : "+v"(wB), "+v"(wD));
            union { int w[4]; bf16x8 v; } u;
            u.w[0] = wA; u.w[1] = wB; u.w[2] = wC; u.w[3] = wD;
            pf[ks] = u.v;
        }
        *(bf16x8*)(sPex + (wk*2 + 0)*1024 + lane*16) = pf[0];
        *(bf16x8*)(sPex + (wk*2 + 1)*1024 + lane*16) = pf[1];
        if (lane < 32) sSt[(wk*2 + 1)*32 + lane] = tsum;

        // issue next-j K half-chunks 0,1 (in flight across exchange+PV)
        if (j + 1 < NJ) {
            kp += 65536;
            #pragma unroll
            for (int t = 0; t < 4; ++t) kf[0][t] = *(const bf16x8*)(kp + KOFF(0, t));
            #pragma unroll
            for (int t = 0; t < 4; ++t) kf[1][t] = *(const bf16x8*)(kp + KOFF(1, t));
        }
        BAR_LGKM();                                             // exchange 2
        float tsum_o = sSt[((wk^1)*2 + 1)*32 + l31];
        float alpha  = upd ? exp2f(m_r - mn) : 1.0f;
        l_r = l_r*alpha + (tsum + tsum_o);
        m_r = mn;
        if (__any(upd)) {               // rescale O (alpha indexed by q-row)
            #pragma unroll
            for (int r = 0; r < 16; ++r) {
                int row = (r&3) + 8*(r>>2) + 4*hi;
                float ar = __shfl(alpha, row);
                #pragma unroll
                for (int n = 0; n < 4; ++n) o[n][r] *= ar;
            }
        }

        // ---- PV: O[dv-half wk] += P(all 64 keys) * V^T; issue V(g+2)
        //      after MFMAs of g (buffer free, drains under next phase) ----
        const char* pb = sPex + lane*16;
        #pragma unroll
        for (int g = 0; g < 4; ++g) {
            bf16x8 pa = ((g >> 1) == wk) ? pf[g & 1]
                        : *(const bf16x8*)(pb + g*1024);
            __builtin_amdgcn_s_setprio(1);
            #pragma unroll
            for (int n = 0; n < 4; ++n)
                o[n] = __builtin_amdgcn_mfma_f32_32x32x16_bf16(
                        pa, vf[g & 1][n], o[n], 0, 0, 0);
            __builtin_amdgcn_s_setprio(0);
            if (g < 2) {
                #pragma unroll
                for (int n = 0; n < 4; ++n)
                    vf[g][n] = *(const bf16x8*)(vp + n*4096 + (g + 2)*1024);
            }
        }
        vp += 32768;
    }
    #undef KOFF

    // ---- epilogue: shared (m,l) across wk; disjoint dv halves -> no merge ----
    const size_t base = (size_t)split * NROWS;
    if (wk == 0 && lane < 32) {
        Mpart[base + q0 + lane] = m_r;      // log2 domain
        Lpart[base + q0 + lane] = l_r;
    }
    #pragma unroll
    for (int r = 0; r < 16; ++r) {
        int row = (r&3) + 8*(r>>2) + 4*hi;
        float* orow = Opart + (base + q0 + row) * (size_t)DVDIM + wk*128;
        #pragma unroll
        for (int n = 0; n < 4; ++n)
            orow[n*32 + l31] = o[n][r];
    }
}

// ---------------------------------------------------------------------------
// Combine NS split partials: out = sum_s(Os*ws) / sum_s(ls*ws), ws=2^(ms-M)
// (Mpart is log2-domain). grid = NROWS/4, block = 256. Coalesced.
// ---------------------------------------------------------------------------
__global__ void combine_splits(
    const float* __restrict__ Opart, const float* __restrict__ Mpart,
    const float* __restrict__ Lpart, float* __restrict__ out)
{
    const int row = blockIdx.x * 4 + (threadIdx.x >> 6);
    const int dv4 = (threadIdx.x & 63) * 4;
    float M = -1e30f;
    #pragma unroll
    for (int s = 0; s < NS; ++s) M = fmaxf(M, Mpart[(size_t)s*NROWS + row]);
    float denom = 0.f;
    float4 acc = make_float4(0.f, 0.f, 0.f, 0.f);
    #pragma unroll
    for (int s = 0; s < NS; ++s) {
        float w = exp2f(Mpart[(size_t)s*NROWS + row] - M);
        denom += Lpart[(size_t)s*NROWS + row] * w;
        float4 ov = *(const float4*)(Opart + ((size_t)s*NROWS + row)*DVDIM + dv4);
        acc.x += ov.x*w; acc.y += ov.y*w; acc.z += ov.z*w; acc.w += ov.w*w;
    }
    float inv = 1.0f / denom;
    *(float4*)(out + (size_t)row*DVDIM + dv4)
        = make_float4(acc.x*inv, acc.y*inv, acc.z*inv, acc.w*inv);
}

extern "C" void kernel_launch(void* const* d_in, const int* in_sizes, int n_in,
                              void* d_out, int out_size, void* d_ws, size_t ws_size,
                              hipStream_t stream) {
    const float* X  = (const float*)d_in[0];   // [8,2048,512]
    const float* Y  = (const float*)d_in[1];   // [4096,512]
    const float* Z  = (const float*)d_in[2];   // [4096,512]
    const float* Wk = (const float*)d_in[3];   // [512,512]
    const float* Wv = (const float*)d_in[4];   // [256,512]
    float* out = (float*)d_out;

    // workspace layout (~38.3 MB)
    char* ws = (char*)d_ws;
    unsigned short* keyb = (unsigned short*)ws;                    // 4 MB, PACKED
    unsigned short* vtb  = (unsigned short*)(ws + (4u<<20));       // 2 MB, PACKED
    float* Opart = (float*)(ws + (6u<<20));                        // NS x 16 MB
    float* Mpart = (float*)(ws + (6u<<20) + (size_t)NS*NROWS*DVDIM*4);
    float* Lpart = Mpart + (size_t)NS*NROWS;

    // both projections, one launch (epilogues emit packed layouts)
    proj_gemms<<<dim3(64, 8, 2), dim3(256), 0, stream>>>(Y, Z, Wk, Wv, keyb, vtb);
    // fused attention: 1024 blocks (4/CU), 2 waves each, coalesced packed K/V
    attn_fused<<<dim3(1024), dim3(128), 0, stream>>>(
        X, keyb, vtb, Opart, Mpart, Lpart);
    // merge splits
    combine_splits<<<dim3(NROWS/4), dim3(256), 0, stream>>>(Opart, Mpart, Lpart, out);
}

// Round 9
// 249.769 us; speedup vs baseline: 1.9138x; 1.0126x over previous
//
#include <hip/hip_runtime.h>
#include <hip/hip_bf16.h>

// Problem constants
#define NB    8
#define SQN   2048
#define SKN   4096
#define DDIM  512
#define DVDIM 256
#define NROWS (NB*SQN)      // 16384
#define NS    2             // SK splits
#define NJ    ((SKN/64)/NS) // 32 j-iterations per split (64 keys each)

typedef __attribute__((ext_vector_type(8)))  short bf16x8;   // 8 bf16 = 4 VGPRs (MFMA A/B frag)
typedef __attribute__((ext_vector_type(4)))  short bf16x4;
typedef __attribute__((ext_vector_type(4)))  float f32x4;    // 16x16 MFMA C/D frag
typedef __attribute__((ext_vector_type(16))) float f32x16;   // 32x32 MFMA C/D frag

// fp32 -> bf16 round-to-nearest-even, bit pattern as short
__device__ __forceinline__ short f2bf(float f) {
    unsigned u = __float_as_uint(f);
    return (short)((u + 0x7FFFu + ((u >> 16) & 1u)) >> 16);
}

// LDS-only barrier: vm loads (K/V register prefetches) stay in flight.
// sched_barrier fences per rule #18 (no hoisting across the asm wait).
#define BAR_LGKM() do {                                                       \
    asm volatile("s_waitcnt lgkmcnt(0)" ::: "memory");                        \
    __builtin_amdgcn_sched_barrier(0);                                        \
    __builtin_amdgcn_s_barrier();                                             \
    __builtin_amdgcn_sched_barrier(0);                                        \
} while (0)

// ---------------------------------------------------------------------------
// Fused projection GEMMs, one launch. grid = (64, 8, 2).  (unchanged from R8)
//  z=0: key[s][d]  = sum_c Y[s][c]*Wk[d][c]   M=4096 N=512
//  z=1: vt[dv][s]  = sum_c Wv[dv][c]*Z[s][c]  M=256  N=4096 (uses 256 of 512 tiles)
// Epilogues write K/V PRE-PACKED in fragment-lane order (16B units;
// lane = hi*32 + l31):
//  K: tile ((J*4+c)*8+tp)*2+kh holds K[J*64+kh*32+l31][c*128+tp*16+hi*8+..7]
//  V: tile (J*8+wv*4+n2)*4+g   holds V^T[wv*128+n2*32+l31][J*64+g*16+hi*8+..7]
// ---------------------------------------------------------------------------
__global__ __launch_bounds__(256, 2) void proj_gemms(
    const float* __restrict__ Y, const float* __restrict__ Z,
    const float* __restrict__ Wk, const float* __restrict__ Wv,
    unsigned short* __restrict__ keyb, unsigned short* __restrict__ vtb)
{
    __shared__ short sA[64*128];   // 16 KB
    __shared__ short sB[64*128];   // 16 KB
    const float *A, *Bm;
    unsigned short* C;
    int m0, n0;
    const bool kpath = (blockIdx.z == 0);
    if (kpath) {
        A = Y; Bm = Wk; C = keyb;
        m0 = blockIdx.x * 64; n0 = blockIdx.y * 64;
    } else {
        int lin = blockIdx.x * 8 + blockIdx.y;
        if (lin >= 256) return;                 // value GEMM needs 256 tiles
        A = Wv; Bm = Z; C = vtb;
        m0 = (lin >> 6) * 64; n0 = (lin & 63) * 64;
    }
    const int tid  = threadIdx.x;
    const int wave = tid >> 6;
    const int lane = tid & 63;
    const int quad = lane >> 4;
    const int l15  = lane & 15;

    f32x4 acc[4];
    #pragma unroll
    for (int n = 0; n < 4; ++n) { acc[n][0]=0.f; acc[n][1]=0.f; acc[n][2]=0.f; acc[n][3]=0.f; }

    float4 ra[8], rb[8];
    #pragma unroll
    for (int it = 0; it < 8; ++it) {            // prefetch kc=0
        int f = it*1024 + tid*4, row = f >> 7, col = f & 127;
        ra[it] = *(const float4*)(A  + (size_t)(m0+row)*DDIM + col);
        rb[it] = *(const float4*)(Bm + (size_t)(n0+row)*DDIM + col);
    }

    for (int kc = 0; kc < DDIM; kc += 128) {
        __syncthreads();                        // LDS free (prev MFMA done)
        #pragma unroll
        for (int it = 0; it < 8; ++it) {
            int f = it*1024 + tid*4;
            bf16x4 a4; a4[0]=f2bf(ra[it].x); a4[1]=f2bf(ra[it].y); a4[2]=f2bf(ra[it].z); a4[3]=f2bf(ra[it].w);
            *(bf16x4*)(sA + f) = a4;
            bf16x4 b4; b4[0]=f2bf(rb[it].x); b4[1]=f2bf(rb[it].y); b4[2]=f2bf(rb[it].z); b4[3]=f2bf(rb[it].w);
            *(bf16x4*)(sB + f) = b4;
        }
        __syncthreads();                        // staged visible
        if (kc + 128 < DDIM) {                  // prefetch kc+1 (in flight under MFMA)
            #pragma unroll
            for (int it = 0; it < 8; ++it) {
                int f = it*1024 + tid*4, row = f >> 7, col = f & 127;
                ra[it] = *(const float4*)(A  + (size_t)(m0+row)*DDIM + kc + 128 + col);
                rb[it] = *(const float4*)(Bm + (size_t)(n0+row)*DDIM + kc + 128 + col);
            }
        }
        #pragma unroll
        for (int t = 0; t < 4; ++t) {
            bf16x8 af = *(const bf16x8*)(sA + (wave*16 + l15)*128 + t*32 + quad*8);
            #pragma unroll
            for (int n = 0; n < 4; ++n) {
                bf16x8 bfr = *(const bf16x8*)(sB + (n*16 + l15)*128 + t*32 + quad*8);
                acc[n] = __builtin_amdgcn_mfma_f32_16x16x32_bf16(af, bfr, acc[n], 0, 0, 0);
            }
        }
    }
    // packed epilogue
    #pragma unroll
    for (int n = 0; n < 4; ++n)
        #pragma unroll
        for (int r = 0; r < 4; ++r) {
            int m  = m0 + wave*16 + quad*4 + r;
            int nn = n0 + n*16 + l15;
            unsigned short v = (unsigned short)f2bf(acc[n][r]);
            size_t off;
            if (kpath) {        // s=m (key row), d=nn
                int J = m >> 6, kh = (m >> 5) & 1, ls = m & 31;
                int c = nn >> 7, tp = (nn >> 4) & 7, hd = (nn >> 3) & 1, d7 = nn & 7;
                off = (size_t)(((J*4 + c)*8 + tp)*2 + kh)*512 + (hd*32 + ls)*8 + d7;
            } else {            // dv=m, key=nn
                int J = nn >> 6, g = (nn >> 4) & 3, hk = (nn >> 3) & 1, k7 = nn & 7;
                int wv = m >> 7, n2 = (m >> 5) & 3, lv = m & 31;
                off = (size_t)((J*8 + wv*4 + n2)*4 + g)*512 + (hk*32 + lv)*8 + k7;
            }
            C[off] = v;
        }
}

// ---------------------------------------------------------------------------
// Fused attention, R9: 64 Q-ROWS PER WAVE (two s-tiles sharing every K/V
// fragment register) -> per-row K/V L2 traffic HALVED (R8 post-mortem:
// kernel was L2-BW-bound at ~20 TB/s aggregate; MFMA only 27% of SIMD
// cycles at the corrected 32 cyc/mfma32x32 cost).
// Block = 128 thr = one wk pair; Q (64 rows) in LDS 64KB; grid = 512
// (2 blocks/CU, 4 waves/CU, 1 wave/SIMD — BW-bound regime, prefetch-deep:
// kf depth-2 ring, ALL FOUR V windows issued during QK h=6/7).
// launch_bounds(128,1): 512 unified regs/wave -> o(128)+s(32) AGPR,
// kf48+vf64+pf16+temps arch VGPR, no spill possible.
// K/V load from R8's PACKED layouts (coalesced 1KB wave-loads to regs).
// T13 defer-max log2-domain softmax; XCD-split keeps K/V L2-resident.
// ---------------------------------------------------------------------------
__global__ __launch_bounds__(128, 1) void attn_fused(
    const float* __restrict__ X,            // [16384][512] fp32
    const unsigned short* __restrict__ Kb,  // key bf16, PACKED (4 MB)
    const unsigned short* __restrict__ Vt,  // V^T bf16, PACKED (2 MB)
    float* __restrict__ Opart,              // [NS][16384][256]
    float* __restrict__ Mpart,              // [NS][16384] (log2 domain)
    float* __restrict__ Lpart)              // [NS][16384]
{
    // 0     : sQ 64KB [rg=2][t2=32][lane]x16B (Q B-frag: row-group rg,
    //         k-step t2: elem e = X[q0+rg*32+l31][t2*16+hi*8+e]*scale)
    // 65536 : sPex 8KB [q32=2][g=4][lane]x16B P A-frags
    // 73728 : sSt 1KB [wk][q32][slot][32] floats
    __shared__ __align__(16) char smem[74752];
    char* sQ   = smem;
    char* sPex = smem + 65536;
    float* sSt = (float*)(smem + 73728);

    const int tid  = threadIdx.x;
    const int wk   = tid >> 6;      // 0..1: key-half for QK / dv-half for PV
    const int lane = tid & 63;
    const int l31  = lane & 31;
    const int hi   = lane >> 5;

    // XCD-split swizzle: bid&7 = XCD; XCD 0-3 -> split 0, 4-7 -> split 1.
    const int bid   = blockIdx.x;          // 0..511
    const int xcd   = bid & 7;
    const int slot  = bid >> 3;            // 0..63
    const int split = xcd >> 2;
    const int q0    = ((xcd & 3)*64 + slot) * 64;   // 64 rows/block
    // 1/sqrt(512) * log2(e): softmax runs in log2 domain (exp2)
    const float scale = 0.04419417382415922f * 1.4426950408889634f;

    // ---- prologue: wave wk stages row-group rg=wk's 32 Q frag-tiles ----
    {
        const float* xrow = X + (size_t)(q0 + wk*32 + l31)*DDIM + hi*8;
        char* qst = sQ + wk*32768;
        #pragma unroll
        for (int t2 = 0; t2 < 32; ++t2) {
            float4 a = *(const float4*)(xrow + t2*16);
            float4 b = *(const float4*)(xrow + t2*16 + 4);
            bf16x8 q;
            q[0]=f2bf(a.x*scale); q[1]=f2bf(a.y*scale); q[2]=f2bf(a.z*scale); q[3]=f2bf(a.w*scale);
            q[4]=f2bf(b.x*scale); q[5]=f2bf(b.y*scale); q[6]=f2bf(b.z*scale); q[7]=f2bf(b.w*scale);
            *(bf16x8*)(qst + t2*1024 + lane*16) = q;
        }
    }

    // O acc: [q32][n] D[row=q][col=dv], dv-half = wk*128 + n*32 + l31. 128 AGPR.
    f32x16 o[2][4];
    #pragma unroll
    for (int g2 = 0; g2 < 2; ++g2)
        #pragma unroll
        for (int n = 0; n < 4; ++n)
            #pragma unroll
            for (int r = 0; r < 16; ++r) o[g2][n][r] = 0.f;
    float m_r[2] = {-1e30f, -1e30f};
    float l_r[2] = {0.f, 0.f};

    // packed base pointers (this wave's key-half / dv-half, lane folded in)
    const int Jg0 = split * NJ;
    const char* kp = (const char*)Kb + (size_t)Jg0*65536 + wk*1024 + lane*16;
    const char* vp = (const char*)Vt + (size_t)Jg0*32768 + wk*16384 + lane*16;
    // K frag (h,t): kp + (h>>1)*16384 + (((h&1)*4+t)*2)*1024
    // V frag (n,g): vp + n*4096 + g*1024
    #define KOFF(h_, t_) ((size_t)((h_)>>1)*16384 + (size_t)((((h_)&1)*4 + (t_))*2)*1024)

    bf16x8 kf[3][4];                    // depth-2 ring (48 VGPR)
    bf16x8 vf[4][4];                    // all 4 PV windows (64 VGPR)

    BAR_LGKM();                         // Q visible to the pair

    // prologue loads: j=0 half-chunks 0,1 -> buf0, buf1
    #pragma unroll
    for (int t = 0; t < 4; ++t) kf[0][t] = *(const bf16x8*)(kp + KOFF(0, t));
    #pragma unroll
    for (int t = 0; t < 4; ++t) kf[1][t] = *(const bf16x8*)(kp + KOFF(1, t));

    const char* qb = sQ + lane*16;

    for (int j = 0; j < NJ; ++j) {
        f32x16 s[2];                    // P^T acc per row-group: D[key][q]
        #pragma unroll
        for (int g2 = 0; g2 < 2; ++g2)
            #pragma unroll
            for (int r = 0; r < 16; ++r) s[g2][r] = 0.f;

        // ---- QK: 8 phases; kf(h+2) issued at phase h (depth-2); ALL four
        //      V windows issued at phases 6/7 (drain under softmax) ----
        #pragma unroll
        for (int h = 0; h < 8; ++h) {
            if (h < 6) {
                #pragma unroll
                for (int t = 0; t < 4; ++t)
                    kf[(h + 2) % 3][t] = *(const bf16x8*)(kp + KOFF(h + 2, t));
            } else {
                #pragma unroll
                for (int gg = 0; gg < 2; ++gg) {
                    const int g = (h - 6)*2 + gg;   // V windows 0,1 / 2,3
                    #pragma unroll
                    for (int n = 0; n < 4; ++n)
                        vf[g][n] = *(const bf16x8*)(vp + n*4096 + g*1024);
                }
            }
            __builtin_amdgcn_s_setprio(1);
            #pragma unroll
            for (int t = 0; t < 4; ++t) {
                #pragma unroll
                for (int g2 = 0; g2 < 2; ++g2) {
                    bf16x8 qv = *(const bf16x8*)(qb + g2*32768 + (h*4 + t)*1024);
                    s[g2] = __builtin_amdgcn_mfma_f32_32x32x16_bf16(
                            kf[h % 3][t], qv, s[g2], 0, 0, 0);
                }
            }
            __builtin_amdgcn_s_setprio(0);
        }

        // ---- softmax (log2 domain), in-lane per row-group; joint max
        //      across wk pair via one LDS exchange ----
        float tmax[2];
        #pragma unroll
        for (int g2 = 0; g2 < 2; ++g2) {
            float v = fmaxf(fmaxf(fmaxf(s[g2][0],s[g2][1]),fmaxf(s[g2][2],s[g2][3])),
                            fmaxf(fmaxf(s[g2][4],s[g2][5]),fmaxf(s[g2][6],s[g2][7])));
            v = fmaxf(v, fmaxf(fmaxf(fmaxf(s[g2][8],s[g2][9]),fmaxf(s[g2][10],s[g2][11])),
                               fmaxf(fmaxf(s[g2][12],s[g2][13]),fmaxf(s[g2][14],s[g2][15]))));
            v = fmaxf(v, __shfl_xor(v, 32));
            tmax[g2] = v;
            if (lane < 32) sSt[((wk*2 + g2)*2 + 0)*32 + lane] = v;
        }
        BAR_LGKM();                                             // exchange 1
        bool  upd[2]; float mn[2], tsum[2];
        #pragma unroll
        for (int g2 = 0; g2 < 2; ++g2) {
            float tmax_o = sSt[(((wk^1)*2 + g2)*2 + 0)*32 + l31];
            float tj = fmaxf(tmax[g2], tmax_o);
            upd[g2] = tj > m_r[g2] + 8.0f;      // T13 defer-max
            mn[g2]  = upd[g2] ? tj : m_r[g2];
            float ts = 0.f;
            #pragma unroll
            for (int r = 0; r < 16; ++r) {
                float pv = exp2f(s[g2][r] - mn[g2]); s[g2][r] = pv; ts += pv;
            }
            ts += __shfl_xor(ts, 32);
            tsum[g2] = ts;
        }

        // P -> PV A-frags in-register per row-group (cvt_pk + permlane32_swap)
        bf16x8 pf[2][2];
        #pragma unroll
        for (int g2 = 0; g2 < 2; ++g2)
            #pragma unroll
            for (int ks = 0; ks < 2; ++ks) {
                int wA, wB, wC, wD;
                asm("v_cvt_pk_bf16_f32 %0, %1, %2" : "=v"(wA) : "v"(s[g2][8*ks+0]), "v"(s[g2][8*ks+1]));
                asm("v_cvt_pk_bf16_f32 %0, %1, %2" : "=v"(wB) : "v"(s[g2][8*ks+2]), "v"(s[g2][8*ks+3]));
                asm("v_cvt_pk_bf16_f32 %0, %1, %2" : "=v"(wC) : "v"(s[g2][8*ks+4]), "v"(s[g2][8*ks+5]));
                asm("v_cvt_pk_bf16_f32 %0, %1, %2" : "=v"(wD) : "v"(s[g2][8*ks+6]), "v"(s[g2][8*ks+7]));
                asm("v_permlane32_swap_b32 %0, %1" : "+v"(wA), "+v"(wC));
                asm("v_permlane32_swap_b32 %0, %1" : "+v"(wB), "+v"(wD));
                union { int w[4]; bf16x8 v; } u;
                u.w[0] = wA; u.w[1] = wB; u.w[2] = wC; u.w[3] = wD;
                pf[g2][ks] = u.v;
                *(bf16x8*)(sPex + (g2*4 + wk*2 + ks)*1024 + lane*16) = u.v;
            }
        #pragma unroll
        for (int g2 = 0; g2 < 2; ++g2)
            if (lane < 32) sSt[((wk*2 + g2)*2 + 1)*32 + lane] = tsum[g2];

        // issue next-j K half-chunks 0,1 (in flight across exchange+PV)
        if (j + 1 < NJ) {
            kp += 65536;
            #pragma unroll
            for (int t = 0; t < 4; ++t) kf[0][t] = *(const bf16x8*)(kp + KOFF(0, t));
            #pragma unroll
            for (int t = 0; t < 4; ++t) kf[1][t] = *(const bf16x8*)(kp + KOFF(1, t));
        }
        BAR_LGKM();                                             // exchange 2
        int any_upd = 0;
        #pragma unroll
        for (int g2 = 0; g2 < 2; ++g2) {
            float tsum_o = sSt[(((wk^1)*2 + g2)*2 + 1)*32 + l31];
            float alpha  = upd[g2] ? exp2f(m_r[g2] - mn[g2]) : 1.0f;
            l_r[g2] = l_r[g2]*alpha + (tsum[g2] + tsum_o);
            m_r[g2] = mn[g2];
            any_upd |= (int)upd[g2];
            if (__any(upd[g2])) {       // rescale O (alpha indexed by q-row)
                #pragma unroll
                for (int r = 0; r < 16; ++r) {
                    int row = (r&3) + 8*(r>>2) + 4*hi;
                    float ar = __shfl(alpha, row);
                    #pragma unroll
                    for (int n = 0; n < 4; ++n) o[g2][n][r] *= ar;
                }
            }
        }

        // ---- PV: O[q32][dv-half wk] += P * V^T; every V frag register is
        //      shared by both row-groups (the 2x traffic amortization) ----
        const char* pb = sPex + lane*16;
        __builtin_amdgcn_s_setprio(1);
        #pragma unroll
        for (int g = 0; g < 4; ++g) {
            bf16x8 pa0 = ((g >> 1) == wk) ? pf[0][g & 1]
                        : *(const bf16x8*)(pb + (0*4 + g)*1024);
            bf16x8 pa1 = ((g >> 1) == wk) ? pf[1][g & 1]
                        : *(const bf16x8*)(pb + (1*4 + g)*1024);
            #pragma unroll
            for (int n = 0; n < 4; ++n) {
                o[0][n] = __builtin_amdgcn_mfma_f32_32x32x16_bf16(
                        pa0, vf[g][n], o[0][n], 0, 0, 0);
                o[1][n] = __builtin_amdgcn_mfma_f32_32x32x16_bf16(
                        pa1, vf[g][n], o[1][n], 0, 0, 0);
            }
        }
        __builtin_amdgcn_s_setprio(0);
        vp += 32768;
    }
    #undef KOFF

    // ---- epilogue: shared (m,l) across wk; disjoint dv halves -> no merge ----
    const size_t base = (size_t)split * NROWS;
    #pragma unroll
    for (int g2 = 0; g2 < 2; ++g2) {
        const int gr0 = q0 + g2*32;
        if (wk == 0 && lane < 32) {
            Mpart[base + gr0 + lane] = m_r[g2];     // log2 domain
            Lpart[base + gr0 + lane] = l_r[g2];
        }
        #pragma unroll
        for (int r = 0; r < 16; ++r) {
            int row = (r&3) + 8*(r>>2) + 4*hi;
            float* orow = Opart + (base + gr0 + row) * (size_t)DVDIM + wk*128;
            #pragma unroll
            for (int n = 0; n < 4; ++n)
                orow[n*32 + l31] = o[g2][n][r];
        }
    }
}

// ---------------------------------------------------------------------------
// Combine NS split partials: out = sum_s(Os*ws) / sum_s(ls*ws), ws=2^(ms-M)
// (Mpart is log2-domain). grid = NROWS/4, block = 256. Coalesced.
// ---------------------------------------------------------------------------
__global__ void combine_splits(
    const float* __restrict__ Opart, const float* __restrict__ Mpart,
    const float* __restrict__ Lpart, float* __restrict__ out)
{
    const int row = blockIdx.x * 4 + (threadIdx.x >> 6);
    const int dv4 = (threadIdx.x & 63) * 4;
    float M = -1e30f;
    #pragma unroll
    for (int s = 0; s < NS; ++s) M = fmaxf(M, Mpart[(size_t)s*NROWS + row]);
    float denom = 0.f;
    float4 acc = make_float4(0.f, 0.f, 0.f, 0.f);
    #pragma unroll
    for (int s = 0; s < NS; ++s) {
        float w = exp2f(Mpart[(size_t)s*NROWS + row] - M);
        denom += Lpart[(size_t)s*NROWS + row] * w;
        float4 ov = *(const float4*)(Opart + ((size_t)s*NROWS + row)*DVDIM + dv4);
        acc.x += ov.x*w; acc.y += ov.y*w; acc.z += ov.z*w; acc.w += ov.w*w;
    }
    float inv = 1.0f / denom;
    *(float4*)(out + (size_t)row*DVDIM + dv4)
        = make_float4(acc.x*inv, acc.y*inv, acc.z*inv, acc.w*inv);
}

extern "C" void kernel_launch(void* const* d_in, const int* in_sizes, int n_in,
                              void* d_out, int out_size, void* d_ws, size_t ws_size,
                              hipStream_t stream) {
    const float* X  = (const float*)d_in[0];   // [8,2048,512]
    const float* Y  = (const float*)d_in[1];   // [4096,512]
    const float* Z  = (const float*)d_in[2];   // [4096,512]
    const float* Wk = (const float*)d_in[3];   // [512,512]
    const float* Wv = (const float*)d_in[4];   // [256,512]
    float* out = (float*)d_out;

    // workspace layout (~38.3 MB)
    char* ws = (char*)d_ws;
    unsigned short* keyb = (unsigned short*)ws;                    // 4 MB, PACKED
    unsigned short* vtb  = (unsigned short*)(ws + (4u<<20));       // 2 MB, PACKED
    float* Opart = (float*)(ws + (6u<<20));                        // NS x 16 MB
    float* Mpart = (float*)(ws + (6u<<20) + (size_t)NS*NROWS*DVDIM*4);
    float* Lpart = Mpart + (size_t)NS*NROWS;

    // both projections, one launch (epilogues emit packed layouts)
    proj_gemms<<<dim3(64, 8, 2), dim3(256), 0, stream>>>(Y, Z, Wk, Wv, keyb, vtb);
    // fused attention: 512 blocks (2/CU), 64 Q-rows/wave, packed K/V to regs
    attn_fused<<<dim3(512), dim3(128), 0, stream>>>(
        X, keyb, vtb, Opart, Mpart, Lpart);
    // merge splits
    combine_splits<<<dim3(NROWS/4), dim3(256), 0, stream>>>(Opart, Mpart, Lpart, out);
}